// Round 10
// baseline (56179.462 us; speedup 1.0000x reference)
//
#include <hip/hip_runtime.h>

#define HID   1024
#define SEQT  8192
#define NBLK  256
#define TPB   512   // 8 waves: widx 0-3 = layer1 rows, widx 4-7 = layer2 rows

// ws (bytes): [0,16K) u64 h1t[2][1024] ; [16K,32K) u64 h2t[2][1024]
// packed slot: (tag<<32)|fp32_bits ; h(s) lives in slot s&1 with tag s+1; init 0
#define WS_BYTES 32768

typedef float v16f __attribute__((ext_vector_type(16)));
typedef unsigned long long u64;

__device__ __forceinline__ float sig_(float x) { return 1.0f / (1.0f + expf(-x)); }

__device__ __forceinline__ u64 ldp(const u64* p) {
    return __hip_atomic_load(p, __ATOMIC_RELAXED, __HIP_MEMORY_SCOPE_AGENT);
}
__device__ __forceinline__ void stp(u64* p, u64 v) {
    __hip_atomic_store(p, v, __ATOMIC_RELAXED, __HIP_MEMORY_SCOPE_AGENT);
}

// Per-element register pin: each weight becomes a loop-carried asm-defined
// scalar -> not rematerializable from memory. (Whole-vector PIN failed: the
// allocator spilled between asm points. Per-element + raised VGPR cap fixes.)
#define PIN16(V)                                                               \
    asm volatile("" : "+v"(V[0]), "+v"(V[1]), "+v"(V[2]), "+v"(V[3]),          \
                      "+v"(V[4]), "+v"(V[5]), "+v"(V[6]), "+v"(V[7]),          \
                      "+v"(V[8]), "+v"(V[9]), "+v"(V[10]), "+v"(V[11]),        \
                      "+v"(V[12]), "+v"(V[13]), "+v"(V[14]), "+v"(V[15]))

extern "C" __global__ void __launch_bounds__(TPB, 1)   // cap 512 VGPR: no spill
lstm_hyb(const float* __restrict__ seq,
         const float* __restrict__ w_ih1, const float* __restrict__ w_hh1,
         const float* __restrict__ b_ih1, const float* __restrict__ b_hh1,
         const float* __restrict__ w_ih2, const float* __restrict__ w_hh2,
         const float* __restrict__ b_ih2, const float* __restrict__ b_hh2,
         const float* __restrict__ w_lin, const float* __restrict__ b_lin,
         float* __restrict__ out, u64* ws)
{
    __shared__ float h1s[HID];    // h1(t-1) values, staged by wave 0
    __shared__ float h2s[HID];    // h2(t-2) values, staged by wave 4
    __shared__ float seqs[SEQT];  // whole input sequence (32 KB)

    const int  lane = threadIdx.x & 63;
    const int  widx = threadIdx.x >> 6;        // 0..7
    const bool isL1 = (widx < 4);
    const int  r    = blockIdx.x * 4 + (widx & 3);   // owned hidden row

    u64* h1t = ws;            // [2][1024]
    u64* h2t = ws + 2048;     // [2][1024]

    for (int i = threadIdx.x; i < SEQT; i += TPB) seqs[i] = seq[i];

    // ---- stationary weights, BRANCH-FREE load + unconditional use ----
    const float* bA  = isL1 ? w_hh1 : w_ih2;
    const float* bB  = isL1 ? w_hh1 : w_hh2;   // L1: B-dot zeroed via zmask
    const float* bbi = isL1 ? b_ih1 : b_ih2;
    const float* bbh = isL1 ? b_hh1 : b_hh2;
    const float  zmask = isL1 ? 0.f : 1.f;
    const float  xsel  = isL1 ? 1.f : 0.f;

    v16f A0, A1, A2, A3, B0, B1, B2, B3;
    {
        const size_t ro = (size_t)r * HID + lane;
        const float *a0 = bA + ro, *a1 = bA + (size_t)HID * HID + ro,
                    *a2 = bA + 2 * (size_t)HID * HID + ro, *a3 = bA + 3 * (size_t)HID * HID + ro;
        const float *b0 = bB + ro, *b1 = bB + (size_t)HID * HID + ro,
                    *b2 = bB + 2 * (size_t)HID * HID + ro, *b3 = bB + 3 * (size_t)HID * HID + ro;
#pragma unroll
        for (int k = 0; k < 16; ++k) {
            A0[k] = a0[64 * k]; A1[k] = a1[64 * k]; A2[k] = a2[64 * k]; A3[k] = a3[64 * k];
            B0[k] = b0[64 * k]; B1[k] = b1[64 * k]; B2[k] = b2[64 * k]; B3[k] = b3[64 * k];
        }
    }
    PIN16(A0); PIN16(A1); PIN16(A2); PIN16(A3);
    PIN16(B0); PIN16(B1); PIN16(B2); PIN16(B3);

    const float wx0 = w_ih1[0 * HID + r], wx1 = w_ih1[1 * HID + r],
                wx2 = w_ih1[2 * HID + r], wx3 = w_ih1[3 * HID + r];
    const float bb0 = bbi[0 * HID + r] + bbh[0 * HID + r];
    const float bb1 = bbi[1 * HID + r] + bbh[1 * HID + r];
    const float bb2 = bbi[2 * HID + r] + bbh[2 * HID + r];
    const float bb3 = bbi[3 * HID + r] + bbh[3 * HID + r];

    const bool carrier = (blockIdx.x == 0 && widx == 7);   // an L2 wave
    v16f WL; float blin = 0.f;
#pragma unroll
    for (int k = 0; k < 16; ++k) WL[k] = 0.f;
    if (carrier) {
#pragma unroll
        for (int k = 0; k < 16; ++k) WL[k] = w_lin[lane + 64 * k];
        blin = b_lin[0];
    }

    u64* pub = isL1 ? h1t : h2t;
    float c = 0.f;

    // Lock-step schedule, one device-wide phase per t (t = 0 .. SEQT+1):
    //   L1  computes h1(t)    [t < SEQT]   from h1(t-1)           (h1s)
    //   L2  computes h2(t-1)  [1<=t<=SEQT] from h1(t-1), h2(t-2)  (h1s,h2s)
    //   OUT computes out(t-2) [t >= 2]     from h2(t-2)           (h2s)
    // Overwrite safety: publishing h1(t) (slot t&1) clobbers h1(t-2); every
    // block reaching step t has seen h2(t-2) FULL, which requires every
    // block's step t-1 publishes, which follow their step t-1 polls -> no
    // block is still reading h1(t-2)/h2(t-3). Hence a slot polled for step t
    // can only hold {stale, final} tags, never a future tag: ONCE VALID it is
    // FINAL -> monotone incremental polling is sound. 8B atomicity: no tears.
    for (int t = 0; t <= SEQT + 1; ++t) {
        PIN16(A0); PIN16(A1); PIN16(A2); PIN16(A3);   // loop-carried: cannot
        PIN16(B0); PIN16(B1); PIN16(B2); PIN16(B3);   // re-load, must stay VGPR

        if (widx == 0 && t <= SEQT) {
            // poll h1(t-1): slot (t+1)&1, tag >= t (t=0: init tag 0 passes)
            const u64* p = h1t + ((t + 1) & 1) * HID + lane;
            unsigned pend = 0xFFFFu;
            u64 q[16];
            int guard = 0;
            while (__any(pend != 0u)) {
#pragma unroll
                for (int k = 0; k < 16; ++k)
                    if (pend & (1u << k)) q[k] = ldp(p + 64 * k);
#pragma unroll
                for (int k = 0; k < 16; ++k)
                    if ((pend & (1u << k)) && (int)(q[k] >> 32) >= t) {
                        h1s[lane + 64 * k] = __uint_as_float((unsigned)q[k]);
                        pend &= ~(1u << k);
                    }
                if (++guard > (1 << 12)) break;   // bounded: fail loud, fast
            }
        }
        if (widx == 4) {
            // poll h2(t-2): slot t&1, tag >= t-1 (t<=1: init tag 0 passes)
            const u64* p = h2t + (t & 1) * HID + lane;
            const int thr = t - 1;
            unsigned pend = 0xFFFFu;
            u64 q[16];
            int guard = 0;
            while (__any(pend != 0u)) {
#pragma unroll
                for (int k = 0; k < 16; ++k)
                    if (pend & (1u << k)) q[k] = ldp(p + 64 * k);
#pragma unroll
                for (int k = 0; k < 16; ++k)
                    if ((pend & (1u << k)) && (int)(q[k] >> 32) >= thr) {
                        h2s[lane + 64 * k] = __uint_as_float((unsigned)q[k]);
                        pend &= ~(1u << k);
                    }
                if (++guard > (1 << 12)) break;
            }
        }
        __syncthreads();

        const bool act = isL1 ? (t < SEQT) : (t >= 1 && t <= SEQT);
        if (act) {
            v16f v1, v2;
#pragma unroll
            for (int k = 0; k < 16; ++k) {
                v1[k] = h1s[lane + 64 * k];
                v2[k] = h2s[lane + 64 * k] * zmask;
            }
            float a0 = 0.f, a1 = 0.f, a2 = 0.f, a3 = 0.f;
#pragma unroll
            for (int k = 0; k < 16; ++k) {
                a0 = fmaf(A0[k], v1[k], a0);
                a1 = fmaf(A1[k], v1[k], a1);
                a2 = fmaf(A2[k], v1[k], a2);
                a3 = fmaf(A3[k], v1[k], a3);
            }
#pragma unroll
            for (int k = 0; k < 16; ++k) {
                a0 = fmaf(B0[k], v2[k], a0);
                a1 = fmaf(B1[k], v2[k], a1);
                a2 = fmaf(B2[k], v2[k], a2);
                a3 = fmaf(B3[k], v2[k], a3);
            }
#pragma unroll
            for (int s = 32; s; s >>= 1) {
                a0 += __shfl_xor(a0, s);
                a1 += __shfl_xor(a1, s);
                a2 += __shfl_xor(a2, s);
                a3 += __shfl_xor(a3, s);
            }
            const float xg = xsel * ((t < SEQT) ? seqs[t] : 0.f);
            float i_ = sig_(a0 + xg * wx0 + bb0);
            float f_ = sig_(a1 + xg * wx1 + bb1);
            float g_ = tanhf(a2 + xg * wx2 + bb2);
            float o_ = sig_(a3 + xg * wx3 + bb3);
            c = f_ * c + i_ * g_;
            float h = o_ * tanhf(c);
            if (lane == 0) {
                const int ps = isL1 ? t : (t - 1);   // produced timestep
                stp(pub + (ps & 1) * HID + r,
                    ((u64)(unsigned)(ps + 1) << 32) | (u64)__float_as_uint(h));
            }
        }

        // out(t-2) from staged h2s
        if (carrier && t >= 2) {
            float ov = 0.f;
#pragma unroll
            for (int k = 0; k < 16; ++k) ov = fmaf(WL[k], h2s[lane + 64 * k], ov);
#pragma unroll
            for (int s = 32; s; s >>= 1) ov += __shfl_xor(ov, s);
            if (lane == 0) out[t - 2] = ov + blin;
        }

        __syncthreads();   // protect LDS from next step's restaging
    }
}

extern "C" void kernel_launch(void* const* d_in, const int* in_sizes, int n_in,
                              void* d_out, int out_size, void* d_ws, size_t ws_size,
                              hipStream_t stream)
{
    (void)hipMemsetAsync(d_ws, 0, WS_BYTES, stream);

    const float* seq  = (const float*)d_in[0];
    const float* wih1 = (const float*)d_in[1];
    const float* whh1 = (const float*)d_in[2];
    const float* bih1 = (const float*)d_in[3];
    const float* bhh1 = (const float*)d_in[4];
    const float* wih2 = (const float*)d_in[5];
    const float* whh2 = (const float*)d_in[6];
    const float* bih2 = (const float*)d_in[7];
    const float* bhh2 = (const float*)d_in[8];
    const float* wlin = (const float*)d_in[9];
    const float* blin = (const float*)d_in[10];
    float* out = (float*)d_out;
    u64*   ws  = (u64*)d_ws;

    hipLaunchKernelGGL(lstm_hyb, dim3(NBLK), dim3(TPB), 0, stream,
                       seq, wih1, whh1, bih1, bhh1,
                       wih2, whh2, bih2, bhh2, wlin, blin,
                       out, ws);
}

// Round 11
// 32054.520 us; speedup vs baseline: 1.7526x; 1.7526x over previous
//
#include <hip/hip_runtime.h>

#define HID   1024
#define SEQT  8192
#define NBLK  256
#define TPB   512   // 8 waves: widx 0-3 = layer1 rows, widx 4-7 = layer2 rows

// ws (bytes): [0,16K) u64 h1t[2][1024] ; [16K,32K) u64 h2t[2][1024] ;
// [32K,32K+8) u32 ep[2] {epoch1, epoch2} ; pad to 64B line
// packed slot: (tag<<32)|fp32_bits ; h(s) lives in slot s&1 with tag s+1; init 0
#define WS_BYTES (32768 + 64)

typedef float v16f __attribute__((ext_vector_type(16)));
typedef unsigned long long u64;
typedef unsigned int u32;

__device__ __forceinline__ float sig_(float x) { return 1.0f / (1.0f + expf(-x)); }

__device__ __forceinline__ u64 ldp(const u64* p) {
    return __hip_atomic_load(p, __ATOMIC_RELAXED, __HIP_MEMORY_SCOPE_AGENT);
}
__device__ __forceinline__ void stp(u64* p, u64 v) {
    __hip_atomic_store(p, v, __ATOMIC_RELAXED, __HIP_MEMORY_SCOPE_AGENT);
}
__device__ __forceinline__ u32 ldu(const u32* p) {
    return __hip_atomic_load(p, __ATOMIC_RELAXED, __HIP_MEMORY_SCOPE_AGENT);
}
__device__ __forceinline__ void stu(u32* p, u32 v) {
    __hip_atomic_store(p, v, __ATOMIC_RELAXED, __HIP_MEMORY_SCOPE_AGENT);
}

extern "C" __global__ void __launch_bounds__(TPB, 2)
lstm_epoch(const float* __restrict__ seq,
           const float* __restrict__ w_ih1, const float* __restrict__ w_hh1,
           const float* __restrict__ b_ih1, const float* __restrict__ b_hh1,
           const float* __restrict__ w_ih2, const float* __restrict__ w_hh2,
           const float* __restrict__ b_ih2, const float* __restrict__ b_hh2,
           const float* __restrict__ w_lin, const float* __restrict__ b_lin,
           float* __restrict__ out, u64* ws)
{
    __shared__ float h1s[HID];    // h1(t-1) values, staged by wave 0
    __shared__ float h2s[HID];    // h2(t-2) values, staged by wave 4
    __shared__ float seqs[SEQT];  // whole input sequence (32 KB)

    const int  lane = threadIdx.x & 63;
    const int  widx = threadIdx.x >> 6;        // 0..7
    const int  blk  = blockIdx.x;
    const bool isL1 = (widx < 4);
    const int  r    = blk * 4 + (widx & 3);    // owned hidden row

    u64* h1t = ws;                 // [2][1024]
    u64* h2t = ws + 2048;          // [2][1024]
    u32* ep  = (u32*)(ws + 4096);  // ep[0]=epoch1, ep[1]=epoch2

    for (int i = threadIdx.x; i < SEQT; i += TPB) seqs[i] = seq[i];

    // ---- stationary weights, BRANCH-FREE load + unconditional use ----
    const float* bA  = isL1 ? w_hh1 : w_ih2;
    const float* bB  = isL1 ? w_hh1 : w_hh2;   // L1: B-dot zeroed via zmask
    const float* bbi = isL1 ? b_ih1 : b_ih2;
    const float* bbh = isL1 ? b_hh1 : b_hh2;
    const float  zmask = isL1 ? 0.f : 1.f;
    const float  xsel  = isL1 ? 1.f : 0.f;

    v16f A0, A1, A2, A3, B0, B1, B2, B3;
    {
        const size_t ro = (size_t)r * HID + lane;
        const float *a0 = bA + ro, *a1 = bA + (size_t)HID * HID + ro,
                    *a2 = bA + 2 * (size_t)HID * HID + ro, *a3 = bA + 3 * (size_t)HID * HID + ro;
        const float *b0 = bB + ro, *b1 = bB + (size_t)HID * HID + ro,
                    *b2 = bB + 2 * (size_t)HID * HID + ro, *b3 = bB + 3 * (size_t)HID * HID + ro;
#pragma unroll
        for (int k = 0; k < 16; ++k) {
            A0[k] = a0[64 * k]; A1[k] = a1[64 * k]; A2[k] = a2[64 * k]; A3[k] = a3[64 * k];
            B0[k] = b0[64 * k]; B1[k] = b1[64 * k]; B2[k] = b2[64 * k]; B3[k] = b3[64 * k];
        }
    }
    const float wx0 = w_ih1[0 * HID + r], wx1 = w_ih1[1 * HID + r],
                wx2 = w_ih1[2 * HID + r], wx3 = w_ih1[3 * HID + r];
    const float bb0 = bbi[0 * HID + r] + bbh[0 * HID + r];
    const float bb1 = bbi[1 * HID + r] + bbh[1 * HID + r];
    const float bb2 = bbi[2 * HID + r] + bbh[2 * HID + r];
    const float bb3 = bbi[3 * HID + r] + bbh[3 * HID + r];

    const bool carrier = (blk == 0 && widx == 7);   // an L2 wave (block 0!)
    v16f WL; float blin = 0.f;
#pragma unroll
    for (int k = 0; k < 16; ++k) WL[k] = 0.f;
    if (carrier) {
#pragma unroll
        for (int k = 0; k < 16; ++k) WL[k] = w_lin[lane + 64 * k];
        blin = b_lin[0];
    }

    u64* pub = isL1 ? h1t : h2t;
    float c = 0.f;

    // Lock-step schedule, one device-wide phase per t (t = 0 .. SEQT+1):
    //   L1  computes h1(t)    [t < SEQT]   from h1(t-1)           (h1s)
    //   L2  computes h2(t-1)  [1<=t<=SEQT] from h1(t-1), h2(t-2)  (h1s,h2s)
    //   OUT computes out(t-2) [t >= 2]     from h2(t-2)           (h2s)
    // Epoch aggregation: ONLY block 0 polls the data regions (its polls double
    // as its own LDS staging). After verifying all tags, it publishes a 4B
    // epoch. Other blocks poll the single epoch word (1 line chip-wide), then
    // do a ONE-SHOT tag-verified data read. Control dependence orders block0's
    // epoch store after its verifying loads; MALL single-point coherence then
    // guarantees consumer reads issued after seeing the epoch observe the
    // data. Tags still self-verify (retry loop) as a safety net.
    // Overwrite safety as before: epoch(t) attests step t-1 completion at all
    // blocks, so slots clobbered at step t have no remaining readers.
    for (int t = 0; t <= SEQT + 1; ++t) {
        if (widx == 0 && t <= SEQT) {
            // need h1(t-1): slot (t+1)&1, tag >= t (t=0: init tag 0 passes)
            const u64* p = h1t + ((t + 1) & 1) * HID + lane;
            if (blk == 0) {
                int guard = 0;
                for (;;) {
                    int mn = 0x7fffffff;
                    u64 q[16];
#pragma unroll
                    for (int k = 0; k < 16; ++k) {
                        q[k] = ldp(p + 64 * k);
                        mn = min(mn, (int)(q[k] >> 32));
                    }
#pragma unroll
                    for (int k = 0; k < 16; ++k)
                        h1s[lane + 64 * k] = __uint_as_float((unsigned)q[k]);
                    if (__all(mn >= t)) break;
                    if (++guard > (1 << 14)) break;   // fail loud, fast
                }
                if (lane == 0) stu(ep + 0, (u32)t);
            } else {
                int guard = 0;
                while ((int)ldu(ep + 0) < t)
                    if (++guard > (1 << 15)) break;
                int guard2 = 0;
                for (;;) {
                    int mn = 0x7fffffff;
                    u64 q[16];
#pragma unroll
                    for (int k = 0; k < 16; ++k) {
                        q[k] = ldp(p + 64 * k);
                        mn = min(mn, (int)(q[k] >> 32));
                    }
#pragma unroll
                    for (int k = 0; k < 16; ++k)
                        h1s[lane + 64 * k] = __uint_as_float((unsigned)q[k]);
                    if (__all(mn >= t)) break;
                    if (++guard2 > (1 << 10)) break;
                }
            }
        }
        if (widx == 4) {
            // need h2(t-2): slot t&1, tag >= t-1 (t<=1: init tag 0 passes)
            const u64* p = h2t + (t & 1) * HID + lane;
            const int thr = t - 1;
            if (blk == 0) {
                int guard = 0;
                for (;;) {
                    int mn = 0x7fffffff;
                    u64 q[16];
#pragma unroll
                    for (int k = 0; k < 16; ++k) {
                        q[k] = ldp(p + 64 * k);
                        mn = min(mn, (int)(q[k] >> 32));
                    }
#pragma unroll
                    for (int k = 0; k < 16; ++k)
                        h2s[lane + 64 * k] = __uint_as_float((unsigned)q[k]);
                    if (__all(mn >= thr)) break;
                    if (++guard > (1 << 14)) break;
                }
                if (lane == 0) stu(ep + 1, (u32)t);
            } else {
                int guard = 0;
                while ((int)ldu(ep + 1) < t)
                    if (++guard > (1 << 15)) break;
                int guard2 = 0;
                for (;;) {
                    int mn = 0x7fffffff;
                    u64 q[16];
#pragma unroll
                    for (int k = 0; k < 16; ++k) {
                        q[k] = ldp(p + 64 * k);
                        mn = min(mn, (int)(q[k] >> 32));
                    }
#pragma unroll
                    for (int k = 0; k < 16; ++k)
                        h2s[lane + 64 * k] = __uint_as_float((unsigned)q[k]);
                    if (__all(mn >= thr)) break;
                    if (++guard2 > (1 << 10)) break;
                }
            }
        }
        __syncthreads();

        const bool act = isL1 ? (t < SEQT) : (t >= 1 && t <= SEQT);
        if (act) {
            v16f v1, v2;
#pragma unroll
            for (int k = 0; k < 16; ++k) {
                v1[k] = h1s[lane + 64 * k];
                v2[k] = h2s[lane + 64 * k] * zmask;
            }
            float a0 = 0.f, a1 = 0.f, a2 = 0.f, a3 = 0.f;
#pragma unroll
            for (int k = 0; k < 16; ++k) {
                a0 = fmaf(A0[k], v1[k], a0);
                a1 = fmaf(A1[k], v1[k], a1);
                a2 = fmaf(A2[k], v1[k], a2);
                a3 = fmaf(A3[k], v1[k], a3);
            }
#pragma unroll
            for (int k = 0; k < 16; ++k) {
                a0 = fmaf(B0[k], v2[k], a0);
                a1 = fmaf(B1[k], v2[k], a1);
                a2 = fmaf(B2[k], v2[k], a2);
                a3 = fmaf(B3[k], v2[k], a3);
            }
#pragma unroll
            for (int s = 32; s; s >>= 1) {
                a0 += __shfl_xor(a0, s);
                a1 += __shfl_xor(a1, s);
                a2 += __shfl_xor(a2, s);
                a3 += __shfl_xor(a3, s);
            }
            const float xg = xsel * ((t < SEQT) ? seqs[t] : 0.f);
            float i_ = sig_(a0 + xg * wx0 + bb0);
            float f_ = sig_(a1 + xg * wx1 + bb1);
            float g_ = tanhf(a2 + xg * wx2 + bb2);
            float o_ = sig_(a3 + xg * wx3 + bb3);
            c = f_ * c + i_ * g_;
            float h = o_ * tanhf(c);
            if (lane == 0) {
                const int ps = isL1 ? t : (t - 1);   // produced timestep
                stp(pub + (ps & 1) * HID + r,
                    ((u64)(unsigned)(ps + 1) << 32) | (u64)__float_as_uint(h));
            }
        }

        // out(t-2) from staged h2s
        if (carrier && t >= 2) {
            float ov = 0.f;
#pragma unroll
            for (int k = 0; k < 16; ++k) ov = fmaf(WL[k], h2s[lane + 64 * k], ov);
#pragma unroll
            for (int s = 32; s; s >>= 1) ov += __shfl_xor(ov, s);
            if (lane == 0) out[t - 2] = ov + blin;
        }

        __syncthreads();   // protect LDS from next step's restaging
    }
}

extern "C" void kernel_launch(void* const* d_in, const int* in_sizes, int n_in,
                              void* d_out, int out_size, void* d_ws, size_t ws_size,
                              hipStream_t stream)
{
    (void)hipMemsetAsync(d_ws, 0, WS_BYTES, stream);

    const float* seq  = (const float*)d_in[0];
    const float* wih1 = (const float*)d_in[1];
    const float* whh1 = (const float*)d_in[2];
    const float* bih1 = (const float*)d_in[3];
    const float* bhh1 = (const float*)d_in[4];
    const float* wih2 = (const float*)d_in[5];
    const float* whh2 = (const float*)d_in[6];
    const float* bih2 = (const float*)d_in[7];
    const float* bhh2 = (const float*)d_in[8];
    const float* wlin = (const float*)d_in[9];
    const float* blin = (const float*)d_in[10];
    float* out = (float*)d_out;
    u64*   ws  = (u64*)d_ws;

    hipLaunchKernelGGL(lstm_epoch, dim3(NBLK), dim3(TPB), 0, stream,
                       seq, wih1, whh1, bih1, bhh1,
                       wih2, whh2, bih2, bhh2, wlin, blin,
                       out, ws);
}